// Round 1
// baseline (1302.096 us; speedup 1.0000x reference)
//
#include <hip/hip_runtime.h>
#include <hip/hip_bf16.h>

#define BN_EPS 1e-5f

typedef __attribute__((ext_vector_type(4))) float f32x4;
typedef __attribute__((ext_vector_type(8))) short short8;

__device__ __forceinline__ unsigned short f2bf(float f) {
  union { float f; unsigned int u; } v; v.f = f;
  unsigned int r = v.u + 0x7fffu + ((v.u >> 16) & 1u);
  return (unsigned short)(r >> 16);
}

__global__ void zero_kernel(float* p, int n) {
  int i = blockIdx.x * blockDim.x + threadIdx.x;
  if (i < n) p[i] = 0.f;
}

// w (DxD f32, row-major [k][j]) -> wt (bf16, transposed [j][k])
__global__ void wconv_kernel(const float* __restrict__ w, unsigned short* __restrict__ wt) {
  int idx = blockIdx.x * blockDim.x + threadIdx.x; // 262144
  int k = idx >> 9, j = idx & 511;
  wt[j * 512 + k] = f2bf(w[idx]);
}

__global__ void copy4_kernel(const float4* __restrict__ s, float4* __restrict__ d, int n) {
  int i = blockIdx.x * blockDim.x + threadIdx.x;
  if (i < n) d[i] = s[i];
}

// h[dst] += x[src] for each edge, per-feature atomics
__global__ void scatter_kernel(const int* __restrict__ ei, const float* __restrict__ xsrc,
                               float* __restrict__ h, int E) {
  int gid = blockIdx.x * blockDim.x + threadIdx.x;
  if (gid >= (E << 9)) return;
  int e = gid >> 9, d = gid & 511;
  int s = ei[e];
  int t = ei[E + e];
  atomicAdd(&h[t * 512 + d], xsrc[s * 512 + d]);
}

// C[M x 512] = act(A[M x 512] @ W[512 x 512] + bias)
// Wt is bf16 transposed [j][k]. A is f32 (converted in-kernel) or bf16.
// 128x128 tile, 4 waves (2x2), each wave 64x64 via 4x4 mfma_f32_16x16x32_bf16.
template<bool ABF16, bool RELU, bool OBF16>
__global__ __launch_bounds__(256) void gemm_kernel(
    const void* __restrict__ Ap, const unsigned short* __restrict__ Wt,
    const float* __restrict__ bias, void* __restrict__ Cp, int M)
{
  __shared__ unsigned short As[128 * 40];  // 32 k + 8 pad per row (80B stride)
  __shared__ unsigned short Bs[128 * 40];

  const int i0 = blockIdx.x * 128;
  const int j0 = blockIdx.y * 128;
  const int tid = threadIdx.x;
  const int lane = tid & 63;
  const int wid = tid >> 6;
  const int wr = wid >> 1, wc = wid & 1;
  const int l15 = lane & 15, lg = lane >> 4;

  f32x4 acc[4][4];
#pragma unroll
  for (int m = 0; m < 4; ++m)
#pragma unroll
    for (int n = 0; n < 4; ++n)
      acc[m][n] = (f32x4){0.f, 0.f, 0.f, 0.f};

  for (int kk = 0; kk < 512; kk += 32) {
    if (kk) __syncthreads();
    // stage B: Bs[col][k] = W[kk+k][j0+col], contiguous 16B from Wt
#pragma unroll
    for (int it = 0; it < 2; ++it) {
      int c = tid + it * 256;
      int col = c >> 2, q = c & 3;
      *(short8*)&Bs[col * 40 + q * 8] =
          *(const short8*)&Wt[(size_t)(j0 + col) * 512 + kk + q * 8];
    }
    // stage A: As[row][k] = A[i0+row][kk+k]
    if (ABF16) {
      const unsigned short* A = (const unsigned short*)Ap;
#pragma unroll
      for (int it = 0; it < 2; ++it) {
        int c = tid + it * 256;
        int row = c >> 2, q = c & 3;
        int gr = i0 + row;
        short8 v = {0, 0, 0, 0, 0, 0, 0, 0};
        if (gr < M) v = *(const short8*)&A[(size_t)gr * 512 + kk + q * 8];
        *(short8*)&As[row * 40 + q * 8] = v;
      }
    } else {
      const float* A = (const float*)Ap;
#pragma unroll
      for (int it = 0; it < 4; ++it) {
        int c = tid + it * 256;
        int row = c >> 3, q = c & 7;
        int gr = i0 + row;
        float4 v = make_float4(0.f, 0.f, 0.f, 0.f);
        if (gr < M) v = *(const float4*)&A[(size_t)gr * 512 + kk + q * 4];
        ushort4 b;
        b.x = f2bf(v.x); b.y = f2bf(v.y); b.z = f2bf(v.z); b.w = f2bf(v.w);
        *(ushort4*)&As[row * 40 + q * 4] = b;
      }
    }
    __syncthreads();

    short8 a[4], b[4];
#pragma unroll
    for (int m = 0; m < 4; ++m)
      a[m] = *(const short8*)&As[(wr * 64 + m * 16 + l15) * 40 + lg * 8];
#pragma unroll
    for (int n = 0; n < 4; ++n)
      b[n] = *(const short8*)&Bs[(wc * 64 + n * 16 + l15) * 40 + lg * 8];
#pragma unroll
    for (int m = 0; m < 4; ++m)
#pragma unroll
      for (int n = 0; n < 4; ++n)
        acc[m][n] = __builtin_amdgcn_mfma_f32_16x16x32_bf16(a[m], b[n], acc[m][n], 0, 0, 0);
  }

  // epilogue: D col = lane&15, row = (lane>>4)*4 + q  [HW-verified mapping]
#pragma unroll
  for (int n = 0; n < 4; ++n) {
    int col = j0 + wc * 64 + n * 16 + l15;
    float bv = bias[col];
#pragma unroll
    for (int m = 0; m < 4; ++m) {
      int row0 = i0 + wr * 64 + m * 16 + lg * 4;
#pragma unroll
      for (int q = 0; q < 4; ++q) {
        int row = row0 + q;
        if (row < M) {
          float v = acc[m][n][q] + bv;
          if (RELU) v = fmaxf(v, 0.f);
          if (OBF16) ((unsigned short*)Cp)[(size_t)row * 512 + col] = f2bf(v);
          else       ((float*)Cp)[(size_t)row * 512 + col] = v;
        }
      }
    }
  }
}

// per-column sum & sumsq over rows [r0, r0+256)
__global__ void stats_kernel(const float* __restrict__ u, float* __restrict__ sum,
                             float* __restrict__ sumsq, int M) {
  int r0 = blockIdx.x * 256;
  int c = threadIdx.x * 2;
  int rend = min(r0 + 256, M);
  float s0 = 0.f, s1 = 0.f, q0 = 0.f, q1 = 0.f;
  for (int r = r0; r < rend; ++r) {
    float2 v = *(const float2*)&u[(size_t)r * 512 + c];
    s0 += v.x; q0 += v.x * v.x;
    s1 += v.y; q1 += v.y * v.y;
  }
  atomicAdd(&sum[c], s0);
  atomicAdd(&sum[c + 1], s1);
  atomicAdd(&sumsq[c], q0);
  atomicAdd(&sumsq[c + 1], q1);
}

__global__ void finalize_kernel(const float* __restrict__ sum, const float* __restrict__ sumsq,
                                const float* __restrict__ gamma, const float* __restrict__ beta,
                                float* __restrict__ scale, float* __restrict__ shift, int M) {
  int c = blockIdx.x * blockDim.x + threadIdx.x;
  if (c < 512) {
    float inv = 1.f / (float)M;
    float mu = sum[c] * inv;
    float var = sumsq[c] * inv - mu * mu;
    float sc = gamma[c] * rsqrtf(var + BN_EPS);
    scale[c] = sc;
    shift[c] = beta[c] - mu * sc;
  }
}

template<bool RES>
__global__ void bn_kernel(const float4* __restrict__ u, const float* __restrict__ scale,
                          const float* __restrict__ shift, const float4* __restrict__ x,
                          float4* __restrict__ y, int n4) {
  int gid = blockIdx.x * blockDim.x + threadIdx.x;
  if (gid >= n4) return;
  int c0 = (gid * 4) & 511;
  float4 uu = u[gid];
  float4 sc = *(const float4*)&scale[c0];
  float4 sh = *(const float4*)&shift[c0];
  float4 r;
  r.x = fmaxf(uu.x * sc.x + sh.x, 0.f);
  r.y = fmaxf(uu.y * sc.y + sh.y, 0.f);
  r.z = fmaxf(uu.z * sc.z + sh.z, 0.f);
  r.w = fmaxf(uu.w * sc.w + sh.w, 0.f);
  if (RES) {
    float4 xx = x[gid];
    r.x += xx.x; r.y += xx.y; r.z += xx.z; r.w += xx.w;
  }
  y[gid] = r;
}

extern "C" void kernel_launch(void* const* d_in, const int* in_sizes, int n_in,
                              void* d_out, int out_size, void* d_ws, size_t ws_size,
                              hipStream_t stream) {
  const float* x   = (const float*)d_in[0];
  const int*   ei  = (const int*)d_in[1];
  const float* w1a = (const float*)d_in[2];
  const float* b1a = (const float*)d_in[3];
  const float* w1b = (const float*)d_in[4];
  const float* b1b = (const float*)d_in[5];
  const float* g1  = (const float*)d_in[6];
  const float* be1 = (const float*)d_in[7];
  const float* w2a = (const float*)d_in[8];
  const float* b2a = (const float*)d_in[9];
  const float* w2b = (const float*)d_in[10];
  const float* b2b = (const float*)d_in[11];
  const float* g2  = (const float*)d_in[12];
  const float* be2 = (const float*)d_in[13];

  const int N = in_sizes[0] / 512;
  const int E = in_sizes[1] / 2;
  const size_t ND = (size_t)N * 512;

  char* ws = (char*)d_ws;
  float* h1          = (float*)ws;                    // ND f32
  float* u1          = (float*)(ws + ND * 4);         // ND f32
  unsigned short* t1 = (unsigned short*)(ws + ND * 8);  // ND bf16
  unsigned short* wt = (unsigned short*)(ws + ND * 10); // 4 x 512x512 bf16
  float* st          = (float*)(ws + ND * 10 + (size_t)4 * 262144 * 2);
  float* sum1 = st,        *sq1 = st + 512;
  float* sum2 = st + 1024, *sq2 = st + 1536;
  float* scale = st + 2048, *shift = st + 2560;

  float* y1 = (float*)d_out;  // layer-1 activation scratch, overwritten at the end

  const int n4 = (int)(ND / 4);
  const int nblk_e = (E * 512 + 255) / 256;
  dim3 ggrid((N + 127) / 128, 4);

  zero_kernel<<<8, 256, 0, stream>>>(st, 2048);
  wconv_kernel<<<1024, 256, 0, stream>>>(w1a, wt);
  wconv_kernel<<<1024, 256, 0, stream>>>(w1b, wt + 262144);
  wconv_kernel<<<1024, 256, 0, stream>>>(w2a, wt + 2 * 262144);
  wconv_kernel<<<1024, 256, 0, stream>>>(w2b, wt + 3 * 262144);

  // ---- layer 1 ----
  copy4_kernel<<<(n4 + 255) / 256, 256, 0, stream>>>((const float4*)x, (float4*)h1, n4);
  scatter_kernel<<<nblk_e, 256, 0, stream>>>(ei, x, h1, E);

  gemm_kernel<false, true, true><<<ggrid, 256, 0, stream>>>(h1, wt, b1a, t1, N);
  gemm_kernel<true, false, false><<<ggrid, 256, 0, stream>>>(t1, wt + 262144, b1b, u1, N);
  stats_kernel<<<(N + 255) / 256, 256, 0, stream>>>(u1, sum1, sq1, N);
  finalize_kernel<<<2, 256, 0, stream>>>(sum1, sq1, g1, be1, scale, shift, N);
  bn_kernel<false><<<(n4 + 255) / 256, 256, 0, stream>>>((const float4*)u1, scale, shift,
                                                         nullptr, (float4*)y1, n4);

  // ---- layer 2 ----
  copy4_kernel<<<(n4 + 255) / 256, 256, 0, stream>>>((const float4*)y1, (float4*)h1, n4);
  scatter_kernel<<<nblk_e, 256, 0, stream>>>(ei, y1, h1, E);

  gemm_kernel<false, true, true><<<ggrid, 256, 0, stream>>>(h1, wt + 2 * 262144, b2a, t1, N);
  gemm_kernel<true, false, false><<<ggrid, 256, 0, stream>>>(t1, wt + 3 * 262144, b2b, u1, N);
  stats_kernel<<<(N + 255) / 256, 256, 0, stream>>>(u1, sum2, sq2, N);
  finalize_kernel<<<2, 256, 0, stream>>>(sum2, sq2, g2, be2, scale, shift, N);
  bn_kernel<true><<<(n4 + 255) / 256, 256, 0, stream>>>((const float4*)u1, scale, shift,
                                                        (const float4*)x, (float4*)d_out, n4);
}

// Round 2
// 740.132 us; speedup vs baseline: 1.7593x; 1.7593x over previous
//
#include <hip/hip_runtime.h>
#include <hip/hip_bf16.h>

#define BN_EPS 1e-5f

typedef __attribute__((ext_vector_type(4))) float f32x4;
typedef __attribute__((ext_vector_type(8))) short short8;

__device__ __forceinline__ unsigned short f2bf(float f) {
  union { float f; unsigned int u; } v; v.f = f;
  unsigned int r = v.u + 0x7fffu + ((v.u >> 16) & 1u);
  return (unsigned short)(r >> 16);
}

__global__ void zero_i32(int* p, int n) {
  int i = blockIdx.x * blockDim.x + threadIdx.x;
  if (i < n) p[i] = 0;
}
__global__ void zero_f32(float* p, int n) {
  int i = blockIdx.x * blockDim.x + threadIdx.x;
  if (i < n) p[i] = 0.f;
}

// w (DxD f32, row-major [k][j]) -> wt (bf16, transposed [j][k])
__global__ void wconv_kernel(const float* __restrict__ w, unsigned short* __restrict__ wt) {
  int idx = blockIdx.x * blockDim.x + threadIdx.x; // 262144
  int k = idx >> 9, j = idx & 511;
  wt[j * 512 + k] = f2bf(w[idx]);
}

// ---- CSR build ----
__global__ void hist_kernel(const int* __restrict__ ei, int* __restrict__ deg, int E) {
  int e = blockIdx.x * blockDim.x + threadIdx.x;
  if (e < E) atomicAdd(&deg[ei[E + e]], 1);
}

// per-block exclusive scan (256 elems), block sums out
__global__ void scan_blk(const int* __restrict__ in, int* __restrict__ loc,
                         int* __restrict__ bsum, int N) {
  __shared__ int tmp[256];
  int tid = threadIdx.x;
  int i = blockIdx.x * 256 + tid;
  int v = (i < N) ? in[i] : 0;
  int acc = v;
  tmp[tid] = v;
  __syncthreads();
  for (int s = 1; s < 256; s <<= 1) {
    int t = (tid >= s) ? tmp[tid - s] : 0;
    __syncthreads();
    acc += t;
    tmp[tid] = acc;
    __syncthreads();
  }
  if (i < N) loc[i] = acc - v;           // exclusive within block
  if (tid == 255) bsum[blockIdx.x] = acc; // block total
}

__global__ void scan_add(const int* __restrict__ loc, const int* __restrict__ bpre,
                         int* __restrict__ off, int* __restrict__ cur, int N, int E) {
  int i = blockIdx.x * 256 + threadIdx.x;
  if (i < N) {
    int o = loc[i] + bpre[blockIdx.x];
    off[i] = o;
    cur[i] = o;
  }
  if (i == 0) off[N] = E;
}

__global__ void fill_kernel(const int* __restrict__ ei, int* __restrict__ cur,
                            int* __restrict__ srcl, int E) {
  int e = blockIdx.x * blockDim.x + threadIdx.x;
  if (e < E) {
    int d = ei[E + e];
    int p = atomicAdd(&cur[d], 1);
    srcl[p] = ei[e];
  }
}

// ---- gather: h[i] = bf16( y(i) + sum_{j in N(i)} y(j) ), y = BN? relu(u*sc+sh) : u
template<bool BN>
__global__ __launch_bounds__(256) void gather_kernel(
    const float* __restrict__ xin, const int* __restrict__ off,
    const int* __restrict__ srcl, const float* __restrict__ scale,
    const float* __restrict__ shift, unsigned short* __restrict__ hout, int N)
{
  int node = blockIdx.x * 4 + (threadIdx.x >> 6);
  if (node >= N) return;
  int c = (threadIdx.x & 63) * 8;

  f32x4 sc0, sc1, sh0, sh1;
  if (BN) {
    sc0 = *(const f32x4*)&scale[c];     sc1 = *(const f32x4*)&scale[c + 4];
    sh0 = *(const f32x4*)&shift[c];     sh1 = *(const f32x4*)&shift[c + 4];
  }

  const float* row = xin + (size_t)node * 512 + c;
  f32x4 a0 = *(const f32x4*)row;
  f32x4 a1 = *(const f32x4*)(row + 4);
  if (BN) {
    a0 = a0 * sc0 + sh0; a1 = a1 * sc1 + sh1;
#pragma unroll
    for (int q = 0; q < 4; ++q) { a0[q] = fmaxf(a0[q], 0.f); a1[q] = fmaxf(a1[q], 0.f); }
  }

  int b = off[node], e = off[node + 1];
  for (int p = b; p < e; ++p) {
    const float* r2 = xin + (size_t)srcl[p] * 512 + c;
    f32x4 v0 = *(const f32x4*)r2;
    f32x4 v1 = *(const f32x4*)(r2 + 4);
    if (BN) {
      v0 = v0 * sc0 + sh0; v1 = v1 * sc1 + sh1;
#pragma unroll
      for (int q = 0; q < 4; ++q) { v0[q] = fmaxf(v0[q], 0.f); v1[q] = fmaxf(v1[q], 0.f); }
    }
    a0 += v0; a1 += v1;
  }

  short8 o;
  o[0] = f2bf(a0[0]); o[1] = f2bf(a0[1]); o[2] = f2bf(a0[2]); o[3] = f2bf(a0[3]);
  o[4] = f2bf(a1[0]); o[5] = f2bf(a1[1]); o[6] = f2bf(a1[2]); o[7] = f2bf(a1[3]);
  *(short8*)&hout[(size_t)node * 512 + c] = o;
}

// ---- GEMM: C[M x 512] = act(A[M x 512] @ W[512 x 512] + bias), A bf16 ----
template<bool RELU, bool OBF16>
__global__ __launch_bounds__(256) void gemm_kernel(
    const unsigned short* __restrict__ A, const unsigned short* __restrict__ Wt,
    const float* __restrict__ bias, void* __restrict__ Cp, int M)
{
  __shared__ unsigned short As[128 * 40];  // 32 k + 8 pad per row (80B stride)
  __shared__ unsigned short Bs[128 * 40];

  const int i0 = blockIdx.x * 128;
  const int j0 = blockIdx.y * 128;
  const int tid = threadIdx.x;
  const int lane = tid & 63;
  const int wid = tid >> 6;
  const int wr = wid >> 1, wc = wid & 1;
  const int l15 = lane & 15, lg = lane >> 4;

  f32x4 acc[4][4];
#pragma unroll
  for (int m = 0; m < 4; ++m)
#pragma unroll
    for (int n = 0; n < 4; ++n)
      acc[m][n] = (f32x4){0.f, 0.f, 0.f, 0.f};

  for (int kk = 0; kk < 512; kk += 32) {
    if (kk) __syncthreads();
#pragma unroll
    for (int it = 0; it < 2; ++it) {
      int c = tid + it * 256;
      int col = c >> 2, q = c & 3;
      *(short8*)&Bs[col * 40 + q * 8] =
          *(const short8*)&Wt[(size_t)(j0 + col) * 512 + kk + q * 8];
    }
#pragma unroll
    for (int it = 0; it < 2; ++it) {
      int c = tid + it * 256;
      int row = c >> 2, q = c & 3;
      int gr = i0 + row;
      short8 v = {0, 0, 0, 0, 0, 0, 0, 0};
      if (gr < M) v = *(const short8*)&A[(size_t)gr * 512 + kk + q * 8];
      *(short8*)&As[row * 40 + q * 8] = v;
    }
    __syncthreads();

    short8 a[4], b[4];
#pragma unroll
    for (int m = 0; m < 4; ++m)
      a[m] = *(const short8*)&As[(wr * 64 + m * 16 + l15) * 40 + lg * 8];
#pragma unroll
    for (int n = 0; n < 4; ++n)
      b[n] = *(const short8*)&Bs[(wc * 64 + n * 16 + l15) * 40 + lg * 8];
#pragma unroll
    for (int m = 0; m < 4; ++m)
#pragma unroll
      for (int n = 0; n < 4; ++n)
        acc[m][n] = __builtin_amdgcn_mfma_f32_16x16x32_bf16(a[m], b[n], acc[m][n], 0, 0, 0);
  }

#pragma unroll
  for (int n = 0; n < 4; ++n) {
    int col = j0 + wc * 64 + n * 16 + l15;
    float bv = bias[col];
#pragma unroll
    for (int m = 0; m < 4; ++m) {
      int row0 = i0 + wr * 64 + m * 16 + lg * 4;
#pragma unroll
      for (int q = 0; q < 4; ++q) {
        int row = row0 + q;
        if (row < M) {
          float v = acc[m][n][q] + bv;
          if (RELU) v = fmaxf(v, 0.f);
          if (OBF16) ((unsigned short*)Cp)[(size_t)row * 512 + col] = f2bf(v);
          else       ((float*)Cp)[(size_t)row * 512 + col] = v;
        }
      }
    }
  }
}

// per-column sum & sumsq over rows [r0, r0+256)
__global__ void stats_kernel(const float* __restrict__ u, float* __restrict__ sum,
                             float* __restrict__ sumsq, int M) {
  int r0 = blockIdx.x * 256;
  int c = threadIdx.x * 2;
  int rend = min(r0 + 256, M);
  float s0 = 0.f, s1 = 0.f, q0 = 0.f, q1 = 0.f;
  for (int r = r0; r < rend; ++r) {
    float2 v = *(const float2*)&u[(size_t)r * 512 + c];
    s0 += v.x; q0 += v.x * v.x;
    s1 += v.y; q1 += v.y * v.y;
  }
  atomicAdd(&sum[c], s0);
  atomicAdd(&sum[c + 1], s1);
  atomicAdd(&sumsq[c], q0);
  atomicAdd(&sumsq[c + 1], q1);
}

__global__ void finalize_kernel(const float* __restrict__ sum, const float* __restrict__ sumsq,
                                const float* __restrict__ gamma, const float* __restrict__ beta,
                                float* __restrict__ scale, float* __restrict__ shift, int M) {
  int c = blockIdx.x * blockDim.x + threadIdx.x;
  if (c < 512) {
    float inv = 1.f / (float)M;
    float mu = sum[c] * inv;
    float var = sumsq[c] * inv - mu * mu;
    float sc = gamma[c] * rsqrtf(var + BN_EPS);
    scale[c] = sc;
    shift[c] = beta[c] - mu * sc;
  }
}

// d_out = relu(u*scale+shift) + x
__global__ void bn_res_kernel(const float4* __restrict__ u, const float* __restrict__ scale,
                              const float* __restrict__ shift, const float4* __restrict__ x,
                              float4* __restrict__ y, int n4) {
  int gid = blockIdx.x * blockDim.x + threadIdx.x;
  if (gid >= n4) return;
  int c0 = (gid * 4) & 511;
  float4 uu = u[gid];
  float4 sc = *(const float4*)&scale[c0];
  float4 sh = *(const float4*)&shift[c0];
  float4 xx = x[gid];
  float4 r;
  r.x = fmaxf(uu.x * sc.x + sh.x, 0.f) + xx.x;
  r.y = fmaxf(uu.y * sc.y + sh.y, 0.f) + xx.y;
  r.z = fmaxf(uu.z * sc.z + sh.z, 0.f) + xx.z;
  r.w = fmaxf(uu.w * sc.w + sh.w, 0.f) + xx.w;
  y[gid] = r;
}

extern "C" void kernel_launch(void* const* d_in, const int* in_sizes, int n_in,
                              void* d_out, int out_size, void* d_ws, size_t ws_size,
                              hipStream_t stream) {
  const float* x   = (const float*)d_in[0];
  const int*   ei  = (const int*)d_in[1];
  const float* w1a = (const float*)d_in[2];
  const float* b1a = (const float*)d_in[3];
  const float* w1b = (const float*)d_in[4];
  const float* b1b = (const float*)d_in[5];
  const float* g1  = (const float*)d_in[6];
  const float* be1 = (const float*)d_in[7];
  const float* w2a = (const float*)d_in[8];
  const float* b2a = (const float*)d_in[9];
  const float* w2b = (const float*)d_in[10];
  const float* b2b = (const float*)d_in[11];
  const float* g2  = (const float*)d_in[12];
  const float* be2 = (const float*)d_in[13];

  const int N = in_sizes[0] / 512;
  const int E = in_sizes[1] / 2;
  const size_t ND = (size_t)N * 512;

  char* ws = (char*)d_ws;
  unsigned short* hbf = (unsigned short*)ws;              // ND bf16
  unsigned short* t1  = (unsigned short*)(ws + ND * 2);   // ND bf16
  float* u            = (float*)(ws + ND * 4);            // ND f32
  unsigned short* wt  = (unsigned short*)(ws + ND * 8);   // 4 x 512x512 bf16
  char* p = ws + ND * 8 + (size_t)4 * 262144 * 2;
  float* st = (float*)p;                                  // 4096 f32
  float* sum1 = st,        *sq1 = st + 512;
  float* sum2 = st + 1024, *sq2 = st + 1536;
  float* scale1 = st + 2048, *shift1 = st + 2560;
  float* scale2 = st + 3072, *shift2 = st + 3584;
  p += 4096 * 4;
  int* deg  = (int*)p;             p += (size_t)(N + 1) * 4;  // also 'loc' reuse? keep separate
  int* off  = (int*)p;             p += (size_t)(N + 1) * 4;
  int* cur  = (int*)p;             p += (size_t)N * 4;
  int* loc  = (int*)p;             p += (size_t)N * 4;
  int* bsum = (int*)p;             p += 256 * 4;
  int* bpre = (int*)p;             p += 256 * 4;
  int* tot  = (int*)p;             p += 4;
  int* srcl = (int*)p;             p += (size_t)E * 4;

  const int n4 = (int)(ND / 4);
  const int nbN = (N + 255) / 256;
  const int nbE = (E + 255) / 256;
  dim3 ggrid((N + 127) / 128, 4);
  const int ggather = (N + 3) / 4;

  // weight prep + zeroing
  wconv_kernel<<<1024, 256, 0, stream>>>(w1a, wt);
  wconv_kernel<<<1024, 256, 0, stream>>>(w1b, wt + 262144);
  wconv_kernel<<<1024, 256, 0, stream>>>(w2a, wt + 2 * 262144);
  wconv_kernel<<<1024, 256, 0, stream>>>(w2b, wt + 3 * 262144);
  zero_f32<<<8, 256, 0, stream>>>(st, 2048);
  zero_i32<<<nbN, 256, 0, stream>>>(deg, N);

  // CSR build
  hist_kernel<<<nbE, 256, 0, stream>>>(ei, deg, E);
  scan_blk<<<nbN, 256, 0, stream>>>(deg, loc, bsum, N);
  scan_blk<<<1, 256, 0, stream>>>(bsum, bpre, tot, nbN);
  scan_add<<<nbN, 256, 0, stream>>>(loc, bpre, off, cur, N, E);
  fill_kernel<<<nbE, 256, 0, stream>>>(ei, cur, srcl, E);

  // ---- layer 1 ----
  gather_kernel<false><<<ggather, 256, 0, stream>>>(x, off, srcl, nullptr, nullptr, hbf, N);
  gemm_kernel<true, true><<<ggrid, 256, 0, stream>>>(hbf, wt, b1a, t1, N);
  gemm_kernel<false, false><<<ggrid, 256, 0, stream>>>(t1, wt + 262144, b1b, u, N);
  stats_kernel<<<nbN, 256, 0, stream>>>(u, sum1, sq1, N);
  finalize_kernel<<<2, 256, 0, stream>>>(sum1, sq1, g1, be1, scale1, shift1, N);

  // ---- layer 2 (BN applied on the fly inside gather) ----
  gather_kernel<true><<<ggather, 256, 0, stream>>>(u, off, srcl, scale1, shift1, hbf, N);
  gemm_kernel<true, true><<<ggrid, 256, 0, stream>>>(hbf, wt + 2 * 262144, b2a, t1, N);
  gemm_kernel<false, false><<<ggrid, 256, 0, stream>>>(t1, wt + 3 * 262144, b2b, u, N);
  stats_kernel<<<nbN, 256, 0, stream>>>(u, sum2, sq2, N);
  finalize_kernel<<<2, 256, 0, stream>>>(sum2, sq2, g2, be2, scale2, shift2, N);
  bn_res_kernel<<<(n4 + 255) / 256, 256, 0, stream>>>((const float4*)u, scale2, shift2,
                                                      (const float4*)x, (float4*)d_out, n4);
}

// Round 3
// 544.472 us; speedup vs baseline: 2.3915x; 1.3594x over previous
//
#include <hip/hip_runtime.h>
#include <hip/hip_bf16.h>

#define BN_EPS 1e-5f

typedef __attribute__((ext_vector_type(4))) float f32x4;
typedef __attribute__((ext_vector_type(8))) short short8;

#define GLL16(gp, lp)                                                        \
  __builtin_amdgcn_global_load_lds(                                          \
      (const __attribute__((address_space(1))) void*)(gp),                   \
      (__attribute__((address_space(3))) void*)(lp), 16, 0, 0)

__device__ __forceinline__ unsigned short f2bf(float f) {
  union { float f; unsigned int u; } v; v.f = f;
  unsigned int r = v.u + 0x7fffu + ((v.u >> 16) & 1u);
  return (unsigned short)(r >> 16);
}

__global__ void zero_i32(int* p, int n) {
  int i = blockIdx.x * blockDim.x + threadIdx.x;
  if (i < n) p[i] = 0;
}
__global__ void zero_f32(float* p, int n) {
  int i = blockIdx.x * blockDim.x + threadIdx.x;
  if (i < n) p[i] = 0.f;
}

// w (DxD f32, row-major [k][j]) -> wt (bf16, transposed [j][k])
__global__ void wconv_kernel(const float* __restrict__ w, unsigned short* __restrict__ wt) {
  int idx = blockIdx.x * blockDim.x + threadIdx.x; // 262144
  int k = idx >> 9, j = idx & 511;
  wt[j * 512 + k] = f2bf(w[idx]);
}

// ---- CSR build ----
__global__ void hist_kernel(const int* __restrict__ ei, int* __restrict__ deg, int E) {
  int e = blockIdx.x * blockDim.x + threadIdx.x;
  if (e < E) atomicAdd(&deg[ei[E + e]], 1);
}

__global__ void scan_blk(const int* __restrict__ in, int* __restrict__ loc,
                         int* __restrict__ bsum, int N) {
  __shared__ int tmp[256];
  int tid = threadIdx.x;
  int i = blockIdx.x * 256 + tid;
  int v = (i < N) ? in[i] : 0;
  int acc = v;
  tmp[tid] = v;
  __syncthreads();
  for (int s = 1; s < 256; s <<= 1) {
    int t = (tid >= s) ? tmp[tid - s] : 0;
    __syncthreads();
    acc += t;
    tmp[tid] = acc;
    __syncthreads();
  }
  if (i < N) loc[i] = acc - v;
  if (tid == 255) bsum[blockIdx.x] = acc;
}

__global__ void scan_add(const int* __restrict__ loc, const int* __restrict__ bpre,
                         int* __restrict__ off, int* __restrict__ cur, int N, int E) {
  int i = blockIdx.x * 256 + threadIdx.x;
  if (i < N) {
    int o = loc[i] + bpre[blockIdx.x];
    off[i] = o;
    cur[i] = o;
  }
  if (i == 0) off[N] = E;
}

__global__ void fill_kernel(const int* __restrict__ ei, int* __restrict__ cur,
                            int* __restrict__ srcl, int E) {
  int e = blockIdx.x * blockDim.x + threadIdx.x;
  if (e < E) {
    int d = ei[E + e];
    int p = atomicAdd(&cur[d], 1);
    srcl[p] = ei[e];
  }
}

// ---- gather: h[i] = bf16( y(i) + sum_{j in N(i)} y(j) ), y = BN? relu(u*sc+sh) : u
template<bool BN>
__global__ __launch_bounds__(256) void gather_kernel(
    const float* __restrict__ xin, const int* __restrict__ off,
    const int* __restrict__ srcl, const float* __restrict__ scale,
    const float* __restrict__ shift, unsigned short* __restrict__ hout, int N)
{
  int node = blockIdx.x * 4 + (threadIdx.x >> 6);
  if (node >= N) return;
  int c = (threadIdx.x & 63) * 8;

  f32x4 sc0, sc1, sh0, sh1;
  if (BN) {
    sc0 = *(const f32x4*)&scale[c];     sc1 = *(const f32x4*)&scale[c + 4];
    sh0 = *(const f32x4*)&shift[c];     sh1 = *(const f32x4*)&shift[c + 4];
  }

  const float* row = xin + (size_t)node * 512 + c;
  f32x4 a0 = *(const f32x4*)row;
  f32x4 a1 = *(const f32x4*)(row + 4);
  if (BN) {
    a0 = a0 * sc0 + sh0; a1 = a1 * sc1 + sh1;
#pragma unroll
    for (int q = 0; q < 4; ++q) { a0[q] = fmaxf(a0[q], 0.f); a1[q] = fmaxf(a1[q], 0.f); }
  }

  int b = off[node], e = off[node + 1];
  for (int p = b; p < e; ++p) {
    const float* r2 = xin + (size_t)srcl[p] * 512 + c;
    f32x4 v0 = *(const f32x4*)r2;
    f32x4 v1 = *(const f32x4*)(r2 + 4);
    if (BN) {
      v0 = v0 * sc0 + sh0; v1 = v1 * sc1 + sh1;
#pragma unroll
      for (int q = 0; q < 4; ++q) { v0[q] = fmaxf(v0[q], 0.f); v1[q] = fmaxf(v1[q], 0.f); }
    }
    a0 += v0; a1 += v1;
  }

  short8 o;
  o[0] = f2bf(a0[0]); o[1] = f2bf(a0[1]); o[2] = f2bf(a0[2]); o[3] = f2bf(a0[3]);
  o[4] = f2bf(a1[0]); o[5] = f2bf(a1[1]); o[6] = f2bf(a1[2]); o[7] = f2bf(a1[3]);
  *(short8*)&hout[(size_t)node * 512 + c] = o;
}

// ---- GEMM: C[M x 512] = act(A[M x 512] @ W[512 x 512] + bias), A bf16 ----
// 128x128 tile, 4 waves (2x2), BK=64, global_load_lds staging with
// pre-swizzled global source (col16' = c ^ (row&7)) and matching swizzled
// ds_read — conflict-free (2-way) fragment reads.
// STATS: per-column sum/sumsq accumulated in epilogue via shfl + atomics.
template<bool RELU, bool OBF16, bool STATS>
__global__ __launch_bounds__(256) void gemm_kernel(
    const unsigned short* __restrict__ A, const unsigned short* __restrict__ Wt,
    const float* __restrict__ bias, void* __restrict__ Cp, int M,
    float* __restrict__ sum, float* __restrict__ sumsq)
{
  __shared__ unsigned short As[128 * 64];
  __shared__ unsigned short Bs[128 * 64];

  const int i0 = blockIdx.x * 128;
  const int j0 = blockIdx.y * 128;
  const int tid = threadIdx.x;
  const int lane = tid & 63;
  const int wid = tid >> 6;
  const int wr = wid >> 1, wc = wid & 1;
  const int l15 = lane & 15, lg = lane >> 4;

  // staging: chunk c (0..15) covers rows c*8..c*8+7; lane l -> row c*8 + (l>>3),
  // lds col16 l&7; global col16 pre-swizzled: (l&7) ^ (row&7) = (l&7)^(l>>3)
  const int srow = lane >> 3;
  const int scol = (lane & 7) ^ srow;
  const unsigned short* gA = A + (size_t)(i0 + srow) * 512 + scol * 8;
  const unsigned short* gB = Wt + (size_t)(j0 + srow) * 512 + scol * 8;

  // fragment read offsets (shorts): row = {wr|wc}*64 + m*16 + l15; row&7 = l15&7
  const int cpr = lg ^ (l15 & 7);
  const int aoff0 = (wr * 64 + l15) * 64 + cpr * 8;
  const int aoff1 = (wr * 64 + l15) * 64 + (cpr ^ 4) * 8;
  const int boff0 = (wc * 64 + l15) * 64 + cpr * 8;
  const int boff1 = (wc * 64 + l15) * 64 + (cpr ^ 4) * 8;

  f32x4 acc[4][4];
#pragma unroll
  for (int m = 0; m < 4; ++m)
#pragma unroll
    for (int n = 0; n < 4; ++n)
      acc[m][n] = (f32x4){0.f, 0.f, 0.f, 0.f};

  for (int kk = 0; kk < 512; kk += 64) {
    if (kk) __syncthreads();
#pragma unroll
    for (int j = 0; j < 4; ++j) {
      int c = wid * 4 + j;
      GLL16(gA + (size_t)c * 4096 + kk, &As[c * 512]);
      GLL16(gB + (size_t)c * 4096 + kk, &Bs[c * 512]);
    }
    __syncthreads();  // compiler drains vmcnt before s_barrier

    short8 a[4][2], b[4][2];
#pragma unroll
    for (int m = 0; m < 4; ++m) {
      a[m][0] = *(const short8*)&As[m * 1024 + aoff0];
      a[m][1] = *(const short8*)&As[m * 1024 + aoff1];
    }
#pragma unroll
    for (int n = 0; n < 4; ++n) {
      b[n][0] = *(const short8*)&Bs[n * 1024 + boff0];
      b[n][1] = *(const short8*)&Bs[n * 1024 + boff1];
    }
#pragma unroll
    for (int ks = 0; ks < 2; ++ks)
#pragma unroll
      for (int m = 0; m < 4; ++m)
#pragma unroll
        for (int n = 0; n < 4; ++n)
          acc[m][n] = __builtin_amdgcn_mfma_f32_16x16x32_bf16(a[m][ks], b[n][ks],
                                                              acc[m][n], 0, 0, 0);
  }

  // epilogue: D col = lane&15, row = (lane>>4)*4 + q
#pragma unroll
  for (int n = 0; n < 4; ++n) {
    int col = j0 + wc * 64 + n * 16 + l15;
    float bv = bias[col];
    float sv = 0.f, qv = 0.f;
#pragma unroll
    for (int m = 0; m < 4; ++m) {
      int row0 = i0 + wr * 64 + m * 16 + lg * 4;
#pragma unroll
      for (int q = 0; q < 4; ++q) {
        int row = row0 + q;
        if (row < M) {
          float v = acc[m][n][q] + bv;
          if (RELU) v = fmaxf(v, 0.f);
          if (STATS) { sv += v; qv += v * v; }
          if (OBF16) ((unsigned short*)Cp)[(size_t)row * 512 + col] = f2bf(v);
          else       ((float*)Cp)[(size_t)row * 512 + col] = v;
        }
      }
    }
    if (STATS) {
      sv += __shfl_xor(sv, 16); qv += __shfl_xor(qv, 16);
      sv += __shfl_xor(sv, 32); qv += __shfl_xor(qv, 32);
      if (lg == 0) {
        atomicAdd(&sum[col], sv);
        atomicAdd(&sumsq[col], qv);
      }
    }
  }
}

__global__ void finalize_kernel(const float* __restrict__ sum, const float* __restrict__ sumsq,
                                const float* __restrict__ gamma, const float* __restrict__ beta,
                                float* __restrict__ scale, float* __restrict__ shift, int M) {
  int c = blockIdx.x * blockDim.x + threadIdx.x;
  if (c < 512) {
    float inv = 1.f / (float)M;
    float mu = sum[c] * inv;
    float var = sumsq[c] * inv - mu * mu;
    float sc = gamma[c] * rsqrtf(var + BN_EPS);
    scale[c] = sc;
    shift[c] = beta[c] - mu * sc;
  }
}

// d_out = relu(u*scale+shift) + x
__global__ void bn_res_kernel(const float4* __restrict__ u, const float* __restrict__ scale,
                              const float* __restrict__ shift, const float4* __restrict__ x,
                              float4* __restrict__ y, int n4) {
  int gid = blockIdx.x * blockDim.x + threadIdx.x;
  if (gid >= n4) return;
  int c0 = (gid * 4) & 511;
  float4 uu = u[gid];
  float4 sc = *(const float4*)&scale[c0];
  float4 sh = *(const float4*)&shift[c0];
  float4 xx = x[gid];
  float4 r;
  r.x = fmaxf(uu.x * sc.x + sh.x, 0.f) + xx.x;
  r.y = fmaxf(uu.y * sc.y + sh.y, 0.f) + xx.y;
  r.z = fmaxf(uu.z * sc.z + sh.z, 0.f) + xx.z;
  r.w = fmaxf(uu.w * sc.w + sh.w, 0.f) + xx.w;
  y[gid] = r;
}

extern "C" void kernel_launch(void* const* d_in, const int* in_sizes, int n_in,
                              void* d_out, int out_size, void* d_ws, size_t ws_size,
                              hipStream_t stream) {
  const float* x   = (const float*)d_in[0];
  const int*   ei  = (const int*)d_in[1];
  const float* w1a = (const float*)d_in[2];
  const float* b1a = (const float*)d_in[3];
  const float* w1b = (const float*)d_in[4];
  const float* b1b = (const float*)d_in[5];
  const float* g1  = (const float*)d_in[6];
  const float* be1 = (const float*)d_in[7];
  const float* w2a = (const float*)d_in[8];
  const float* b2a = (const float*)d_in[9];
  const float* w2b = (const float*)d_in[10];
  const float* b2b = (const float*)d_in[11];
  const float* g2  = (const float*)d_in[12];
  const float* be2 = (const float*)d_in[13];

  const int N = in_sizes[0] / 512;
  const int E = in_sizes[1] / 2;
  const size_t ND = (size_t)N * 512;

  char* ws = (char*)d_ws;
  unsigned short* hbf = (unsigned short*)ws;              // ND bf16
  unsigned short* t1  = (unsigned short*)(ws + ND * 2);   // ND bf16
  float* u            = (float*)(ws + ND * 4);            // ND f32
  unsigned short* wt  = (unsigned short*)(ws + ND * 8);   // 4 x 512x512 bf16
  char* p = ws + ND * 8 + (size_t)4 * 262144 * 2;
  float* st = (float*)p;                                  // 4096 f32
  float* sum1 = st,        *sq1 = st + 512;
  float* sum2 = st + 1024, *sq2 = st + 1536;
  float* scale1 = st + 2048, *shift1 = st + 2560;
  float* scale2 = st + 3072, *shift2 = st + 3584;
  p += 4096 * 4;
  int* deg  = (int*)p;             p += (size_t)(N + 1) * 4;
  int* off  = (int*)p;             p += (size_t)(N + 1) * 4;
  int* cur  = (int*)p;             p += (size_t)N * 4;
  int* loc  = (int*)p;             p += (size_t)N * 4;
  int* bsum = (int*)p;             p += 256 * 4;
  int* bpre = (int*)p;             p += 256 * 4;
  int* tot  = (int*)p;             p += 4;
  int* srcl = (int*)p;             p += (size_t)E * 4;

  const int n4 = (int)(ND / 4);
  const int nbN = (N + 255) / 256;
  const int nbE = (E + 255) / 256;
  dim3 ggrid((N + 127) / 128, 4);
  const int ggather = (N + 3) / 4;

  // weight prep + zeroing
  wconv_kernel<<<1024, 256, 0, stream>>>(w1a, wt);
  wconv_kernel<<<1024, 256, 0, stream>>>(w1b, wt + 262144);
  wconv_kernel<<<1024, 256, 0, stream>>>(w2a, wt + 2 * 262144);
  wconv_kernel<<<1024, 256, 0, stream>>>(w2b, wt + 3 * 262144);
  zero_f32<<<8, 256, 0, stream>>>(st, 2048);
  zero_i32<<<nbN, 256, 0, stream>>>(deg, N);

  // CSR build
  hist_kernel<<<nbE, 256, 0, stream>>>(ei, deg, E);
  scan_blk<<<nbN, 256, 0, stream>>>(deg, loc, bsum, N);
  scan_blk<<<1, 256, 0, stream>>>(bsum, bpre, tot, nbN);
  scan_add<<<nbN, 256, 0, stream>>>(loc, bpre, off, cur, N, E);
  fill_kernel<<<nbE, 256, 0, stream>>>(ei, cur, srcl, E);

  // ---- layer 1 ----
  gather_kernel<false><<<ggather, 256, 0, stream>>>(x, off, srcl, nullptr, nullptr, hbf, N);
  gemm_kernel<true, true, false><<<ggrid, 256, 0, stream>>>(hbf, wt, b1a, t1, N,
                                                            nullptr, nullptr);
  gemm_kernel<false, false, true><<<ggrid, 256, 0, stream>>>(t1, wt + 262144, b1b, u, N,
                                                             sum1, sq1);
  finalize_kernel<<<2, 256, 0, stream>>>(sum1, sq1, g1, be1, scale1, shift1, N);

  // ---- layer 2 (BN applied on the fly inside gather) ----
  gather_kernel<true><<<ggather, 256, 0, stream>>>(u, off, srcl, scale1, shift1, hbf, N);
  gemm_kernel<true, true, false><<<ggrid, 256, 0, stream>>>(hbf, wt + 2 * 262144, b2a, t1, N,
                                                            nullptr, nullptr);
  gemm_kernel<false, false, true><<<ggrid, 256, 0, stream>>>(t1, wt + 3 * 262144, b2b, u, N,
                                                             sum2, sq2);
  finalize_kernel<<<2, 256, 0, stream>>>(sum2, sq2, g2, be2, scale2, shift2, N);
  bn_res_kernel<<<(n4 + 255) / 256, 256, 0, stream>>>((const float4*)u, scale2, shift2,
                                                      (const float4*)x, (float4*)d_out, n4);
}

// Round 4
// 504.708 us; speedup vs baseline: 2.5799x; 1.0788x over previous
//
#include <hip/hip_runtime.h>
#include <hip/hip_bf16.h>

#define BN_EPS 1e-5f

typedef __attribute__((ext_vector_type(4))) float f32x4;
typedef __attribute__((ext_vector_type(8))) short short8;

#define GLL16(gp, lp)                                                        \
  __builtin_amdgcn_global_load_lds(                                          \
      (const __attribute__((address_space(1))) void*)(gp),                   \
      (__attribute__((address_space(3))) void*)(lp), 16, 0, 0)

__device__ __forceinline__ unsigned short f2bf(float f) {
  union { float f; unsigned int u; } v; v.f = f;
  unsigned int r = v.u + 0x7fffu + ((v.u >> 16) & 1u);
  return (unsigned short)(r >> 16);
}

__global__ void zero_i32(int* p, int n) {
  int i = blockIdx.x * blockDim.x + threadIdx.x;
  if (i < n) p[i] = 0;
}
__global__ void zero_f32(float* p, int n) {
  int i = blockIdx.x * blockDim.x + threadIdx.x;
  if (i < n) p[i] = 0.f;
}

// w (DxD f32, row-major [k][j]) -> wt (bf16, transposed [j][k])
__global__ void wconv_kernel(const float* __restrict__ w, unsigned short* __restrict__ wt) {
  int idx = blockIdx.x * blockDim.x + threadIdx.x; // 262144
  int k = idx >> 9, j = idx & 511;
  wt[j * 512 + k] = f2bf(w[idx]);
}

// ---- CSR build ----
__global__ void hist_kernel(const int* __restrict__ ei, int* __restrict__ deg, int E) {
  int e = blockIdx.x * blockDim.x + threadIdx.x;
  if (e < E) atomicAdd(&deg[ei[E + e]], 1);
}

__global__ void scan_blk(const int* __restrict__ in, int* __restrict__ loc,
                         int* __restrict__ bsum, int N) {
  __shared__ int tmp[256];
  int tid = threadIdx.x;
  int i = blockIdx.x * 256 + tid;
  int v = (i < N) ? in[i] : 0;
  int acc = v;
  tmp[tid] = v;
  __syncthreads();
  for (int s = 1; s < 256; s <<= 1) {
    int t = (tid >= s) ? tmp[tid - s] : 0;
    __syncthreads();
    acc += t;
    tmp[tid] = acc;
    __syncthreads();
  }
  if (i < N) loc[i] = acc - v;
  if (tid == 255) bsum[blockIdx.x] = acc;
}

__global__ void scan_add(const int* __restrict__ loc, const int* __restrict__ bpre,
                         int* __restrict__ off, int* __restrict__ cur, int N, int E) {
  int i = blockIdx.x * 256 + threadIdx.x;
  if (i < N) {
    int o = loc[i] + bpre[blockIdx.x];
    off[i] = o;
    cur[i] = o;
  }
  if (i == 0) off[N] = E;
}

__global__ void fill_kernel(const int* __restrict__ ei, int* __restrict__ cur,
                            int* __restrict__ srcl, int E) {
  int e = blockIdx.x * blockDim.x + threadIdx.x;
  if (e < E) {
    int d = ei[E + e];
    int p = atomicAdd(&cur[d], 1);
    srcl[p] = ei[e];
  }
}

// ---- gather: h[i] = bf16( y(i) + sum_{j in N(i)} y(j) ), y = BN? relu(u*sc+sh) : u
template<bool BN>
__global__ __launch_bounds__(256) void gather_kernel(
    const float* __restrict__ xin, const int* __restrict__ off,
    const int* __restrict__ srcl, const float* __restrict__ scale,
    const float* __restrict__ shift, unsigned short* __restrict__ hout, int N)
{
  int node = blockIdx.x * 4 + (threadIdx.x >> 6);
  if (node >= N) return;
  int c = (threadIdx.x & 63) * 8;

  f32x4 sc0, sc1, sh0, sh1;
  if (BN) {
    sc0 = *(const f32x4*)&scale[c];     sc1 = *(const f32x4*)&scale[c + 4];
    sh0 = *(const f32x4*)&shift[c];     sh1 = *(const f32x4*)&shift[c + 4];
  }

  const float* row = xin + (size_t)node * 512 + c;
  f32x4 a0 = *(const f32x4*)row;
  f32x4 a1 = *(const f32x4*)(row + 4);
  if (BN) {
    a0 = a0 * sc0 + sh0; a1 = a1 * sc1 + sh1;
#pragma unroll
    for (int q = 0; q < 4; ++q) { a0[q] = fmaxf(a0[q], 0.f); a1[q] = fmaxf(a1[q], 0.f); }
  }

  int b = off[node], e = off[node + 1];
  for (int p = b; p < e; ++p) {
    const float* r2 = xin + (size_t)srcl[p] * 512 + c;
    f32x4 v0 = *(const f32x4*)r2;
    f32x4 v1 = *(const f32x4*)(r2 + 4);
    if (BN) {
      v0 = v0 * sc0 + sh0; v1 = v1 * sc1 + sh1;
#pragma unroll
      for (int q = 0; q < 4; ++q) { v0[q] = fmaxf(v0[q], 0.f); v1[q] = fmaxf(v1[q], 0.f); }
    }
    a0 += v0; a1 += v1;
  }

  short8 o;
  o[0] = f2bf(a0[0]); o[1] = f2bf(a0[1]); o[2] = f2bf(a0[2]); o[3] = f2bf(a0[3]);
  o[4] = f2bf(a1[0]); o[5] = f2bf(a1[1]); o[6] = f2bf(a1[2]); o[7] = f2bf(a1[3]);
  *(short8*)&hout[(size_t)node * 512 + c] = o;
}

// ---- GEMM: C[M x 512] = act(A[M x 512] @ W[512 x 512] + bias), A bf16 ----
// 128x128 tile, 4 waves (2x2), BK=64, double-buffered LDS (T3 minimum-2-phase:
// stage next tile BEFORE computing current; single __syncthreads per K-step
// = the recipe's vmcnt(0)+barrier). global_load_lds with pre-swizzled global
// source (col16' = c ^ (row&7)) + matching swizzled ds_read (conflict-free).
// 1D grid, i-major tile order + bijective XCD-chunked swizzle for A L2 reuse.
// STATS: per-column sum/sumsq accumulated in epilogue via shfl + atomics.
template<bool RELU, bool OBF16, bool STATS>
__global__ __launch_bounds__(256) void gemm_kernel(
    const unsigned short* __restrict__ A, const unsigned short* __restrict__ Wt,
    const float* __restrict__ bias, void* __restrict__ Cp, int M, int nwg,
    float* __restrict__ sum, float* __restrict__ sumsq)
{
  // S[buf][0]=A tile, S[buf][1]=B tile; each 128 rows x 64 cols bf16 = 16KB
  __shared__ unsigned short S[2][2][8192];

  // XCD-chunked bijective swizzle (m204), i-major tile order
  const int bid = blockIdx.x;
  const int xcd = bid & 7, pos = bid >> 3;
  const int q8 = nwg >> 3, r8 = nwg & 7;
  const int base = (xcd < r8) ? xcd * (q8 + 1) : r8 * (q8 + 1) + (xcd - r8) * q8;
  const int wg = base + pos;
  const int i0 = (wg >> 2) * 128;
  const int j0 = (wg & 3) * 128;

  const int tid = threadIdx.x;
  const int lane = tid & 63;
  const int wid = tid >> 6;
  const int wr = wid >> 1, wc = wid & 1;
  const int l15 = lane & 15, lg = lane >> 4;

  // staging: chunk c (0..15) covers rows c*8..c*8+7; lane l -> row c*8 + (l>>3),
  // lds col16 l&7; global col16 pre-swizzled: (l&7) ^ (row&7) = (l&7)^(l>>3)
  const int srow = lane >> 3;
  const int scol = (lane & 7) ^ srow;
  const unsigned short* gA = A + (size_t)(i0 + srow) * 512 + scol * 8;
  const unsigned short* gB = Wt + (size_t)(j0 + srow) * 512 + scol * 8;

  // fragment read offsets (shorts): row = {wr|wc}*64 + m*16 + l15; row&7 = l15&7
  const int cpr = lg ^ (l15 & 7);
  const int aoff0 = (wr * 64 + l15) * 64 + cpr * 8;
  const int aoff1 = (wr * 64 + l15) * 64 + (cpr ^ 4) * 8;
  const int boff0 = (wc * 64 + l15) * 64 + cpr * 8;
  const int boff1 = (wc * 64 + l15) * 64 + (cpr ^ 4) * 8;

  f32x4 acc[4][4];
#pragma unroll
  for (int m = 0; m < 4; ++m)
#pragma unroll
    for (int n = 0; n < 4; ++n)
      acc[m][n] = (f32x4){0.f, 0.f, 0.f, 0.f};

  // prologue: stage K-tile 0 into buf 0
#pragma unroll
  for (int j = 0; j < 4; ++j) {
    int c = wid * 4 + j;
    GLL16(gA + (size_t)c * 4096, &S[0][0][c * 512]);
    GLL16(gB + (size_t)c * 4096, &S[0][1][c * 512]);
  }
  __syncthreads();

#pragma unroll
  for (int kt = 0; kt < 8; ++kt) {
    const int cur = kt & 1;
    if (kt < 7) {
      const int nxt = cur ^ 1;
      const int kk = (kt + 1) * 64;
#pragma unroll
      for (int j = 0; j < 4; ++j) {
        int c = wid * 4 + j;
        GLL16(gA + (size_t)c * 4096 + kk, &S[nxt][0][c * 512]);
        GLL16(gB + (size_t)c * 4096 + kk, &S[nxt][1][c * 512]);
      }
    }

    short8 a[4][2], b[4][2];
#pragma unroll
    for (int m = 0; m < 4; ++m) {
      a[m][0] = *(const short8*)&S[cur][0][m * 1024 + aoff0];
      a[m][1] = *(const short8*)&S[cur][0][m * 1024 + aoff1];
    }
#pragma unroll
    for (int n = 0; n < 4; ++n) {
      b[n][0] = *(const short8*)&S[cur][1][n * 1024 + boff0];
      b[n][1] = *(const short8*)&S[cur][1][n * 1024 + boff1];
    }
#pragma unroll
    for (int ks = 0; ks < 2; ++ks)
#pragma unroll
      for (int m = 0; m < 4; ++m)
#pragma unroll
        for (int n = 0; n < 4; ++n)
          acc[m][n] = __builtin_amdgcn_mfma_f32_16x16x32_bf16(a[m][ks], b[n][ks],
                                                              acc[m][n], 0, 0, 0);
    __syncthreads();  // drains vmcnt(0)+lgkmcnt(0): next-tile loads flew during MFMA
  }

  // epilogue: D col = lane&15, row = (lane>>4)*4 + q
#pragma unroll
  for (int n = 0; n < 4; ++n) {
    int col = j0 + wc * 64 + n * 16 + l15;
    float bv = bias[col];
    float sv = 0.f, qv = 0.f;
#pragma unroll
    for (int m = 0; m < 4; ++m) {
      int row0 = i0 + wr * 64 + m * 16 + lg * 4;
#pragma unroll
      for (int q = 0; q < 4; ++q) {
        int row = row0 + q;
        if (row < M) {
          float v = acc[m][n][q] + bv;
          if (RELU) v = fmaxf(v, 0.f);
          if (STATS) { sv += v; qv += v * v; }
          if (OBF16) ((unsigned short*)Cp)[(size_t)row * 512 + col] = f2bf(v);
          else       ((float*)Cp)[(size_t)row * 512 + col] = v;
        }
      }
    }
    if (STATS) {
      sv += __shfl_xor(sv, 16); qv += __shfl_xor(qv, 16);
      sv += __shfl_xor(sv, 32); qv += __shfl_xor(qv, 32);
      if (lg == 0) {
        atomicAdd(&sum[col], sv);
        atomicAdd(&sumsq[col], qv);
      }
    }
  }
}

__global__ void finalize_kernel(const float* __restrict__ sum, const float* __restrict__ sumsq,
                                const float* __restrict__ gamma, const float* __restrict__ beta,
                                float* __restrict__ scale, float* __restrict__ shift, int M) {
  int c = blockIdx.x * blockDim.x + threadIdx.x;
  if (c < 512) {
    float inv = 1.f / (float)M;
    float mu = sum[c] * inv;
    float var = sumsq[c] * inv - mu * mu;
    float sc = gamma[c] * rsqrtf(var + BN_EPS);
    scale[c] = sc;
    shift[c] = beta[c] - mu * sc;
  }
}

// d_out = relu(u*scale+shift) + x
__global__ void bn_res_kernel(const float4* __restrict__ u, const float* __restrict__ scale,
                              const float* __restrict__ shift, const float4* __restrict__ x,
                              float4* __restrict__ y, int n4) {
  int gid = blockIdx.x * blockDim.x + threadIdx.x;
  if (gid >= n4) return;
  int c0 = (gid * 4) & 511;
  float4 uu = u[gid];
  float4 sc = *(const float4*)&scale[c0];
  float4 sh = *(const float4*)&shift[c0];
  float4 xx = x[gid];
  float4 r;
  r.x = fmaxf(uu.x * sc.x + sh.x, 0.f) + xx.x;
  r.y = fmaxf(uu.y * sc.y + sh.y, 0.f) + xx.y;
  r.z = fmaxf(uu.z * sc.z + sh.z, 0.f) + xx.z;
  r.w = fmaxf(uu.w * sc.w + sh.w, 0.f) + xx.w;
  y[gid] = r;
}

extern "C" void kernel_launch(void* const* d_in, const int* in_sizes, int n_in,
                              void* d_out, int out_size, void* d_ws, size_t ws_size,
                              hipStream_t stream) {
  const float* x   = (const float*)d_in[0];
  const int*   ei  = (const int*)d_in[1];
  const float* w1a = (const float*)d_in[2];
  const float* b1a = (const float*)d_in[3];
  const float* w1b = (const float*)d_in[4];
  const float* b1b = (const float*)d_in[5];
  const float* g1  = (const float*)d_in[6];
  const float* be1 = (const float*)d_in[7];
  const float* w2a = (const float*)d_in[8];
  const float* b2a = (const float*)d_in[9];
  const float* w2b = (const float*)d_in[10];
  const float* b2b = (const float*)d_in[11];
  const float* g2  = (const float*)d_in[12];
  const float* be2 = (const float*)d_in[13];

  const int N = in_sizes[0] / 512;
  const int E = in_sizes[1] / 2;
  const size_t ND = (size_t)N * 512;

  char* ws = (char*)d_ws;
  unsigned short* hbf = (unsigned short*)ws;              // ND bf16
  unsigned short* t1  = (unsigned short*)(ws + ND * 2);   // ND bf16
  float* u            = (float*)(ws + ND * 4);            // ND f32
  unsigned short* wt  = (unsigned short*)(ws + ND * 8);   // 4 x 512x512 bf16
  char* p = ws + ND * 8 + (size_t)4 * 262144 * 2;
  float* st = (float*)p;                                  // 4096 f32
  float* sum1 = st,        *sq1 = st + 512;
  float* sum2 = st + 1024, *sq2 = st + 1536;
  float* scale1 = st + 2048, *shift1 = st + 2560;
  float* scale2 = st + 3072, *shift2 = st + 3584;
  p += 4096 * 4;
  int* deg  = (int*)p;             p += (size_t)(N + 1) * 4;
  int* off  = (int*)p;             p += (size_t)(N + 1) * 4;
  int* cur  = (int*)p;             p += (size_t)N * 4;
  int* loc  = (int*)p;             p += (size_t)N * 4;
  int* bsum = (int*)p;             p += 256 * 4;
  int* bpre = (int*)p;             p += 256 * 4;
  int* tot  = (int*)p;             p += 4;
  int* srcl = (int*)p;             p += (size_t)E * 4;

  const int n4 = (int)(ND / 4);
  const int nbN = (N + 255) / 256;
  const int nbE = (E + 255) / 256;
  const int nwg = ((N + 127) / 128) * 4;
  const int ggather = (N + 3) / 4;

  // weight prep + zeroing
  wconv_kernel<<<1024, 256, 0, stream>>>(w1a, wt);
  wconv_kernel<<<1024, 256, 0, stream>>>(w1b, wt + 262144);
  wconv_kernel<<<1024, 256, 0, stream>>>(w2a, wt + 2 * 262144);
  wconv_kernel<<<1024, 256, 0, stream>>>(w2b, wt + 3 * 262144);
  zero_f32<<<8, 256, 0, stream>>>(st, 2048);
  zero_i32<<<nbN, 256, 0, stream>>>(deg, N);

  // CSR build
  hist_kernel<<<nbE, 256, 0, stream>>>(ei, deg, E);
  scan_blk<<<nbN, 256, 0, stream>>>(deg, loc, bsum, N);
  scan_blk<<<1, 256, 0, stream>>>(bsum, bpre, tot, nbN);
  scan_add<<<nbN, 256, 0, stream>>>(loc, bpre, off, cur, N, E);
  fill_kernel<<<nbE, 256, 0, stream>>>(ei, cur, srcl, E);

  // ---- layer 1 ----
  gather_kernel<false><<<ggather, 256, 0, stream>>>(x, off, srcl, nullptr, nullptr, hbf, N);
  gemm_kernel<true, true, false><<<nwg, 256, 0, stream>>>(hbf, wt, b1a, t1, N, nwg,
                                                          nullptr, nullptr);
  gemm_kernel<false, false, true><<<nwg, 256, 0, stream>>>(t1, wt + 262144, b1b, u, N, nwg,
                                                           sum1, sq1);
  finalize_kernel<<<2, 256, 0, stream>>>(sum1, sq1, g1, be1, scale1, shift1, N);

  // ---- layer 2 (BN applied on the fly inside gather) ----
  gather_kernel<true><<<ggather, 256, 0, stream>>>(u, off, srcl, scale1, shift1, hbf, N);
  gemm_kernel<true, true, false><<<nwg, 256, 0, stream>>>(hbf, wt + 2 * 262144, b2a, t1, N,
                                                          nwg, nullptr, nullptr);
  gemm_kernel<false, false, true><<<nwg, 256, 0, stream>>>(t1, wt + 3 * 262144, b2b, u, N,
                                                           nwg, sum2, sq2);
  finalize_kernel<<<2, 256, 0, stream>>>(sum2, sq2, g2, be2, scale2, shift2, N);
  bn_res_kernel<<<(n4 + 255) / 256, 256, 0, stream>>>((const float4*)u, scale2, shift2,
                                                      (const float4*)x, (float4*)d_out, n4);
}

// Round 5
// 382.500 us; speedup vs baseline: 3.4042x; 1.3195x over previous
//
#include <hip/hip_runtime.h>
#include <hip/hip_bf16.h>

#define BN_EPS 1e-5f

typedef __attribute__((ext_vector_type(4))) float f32x4;
typedef __attribute__((ext_vector_type(8))) short short8;

#define GLL16(gp, lp)                                                        \
  __builtin_amdgcn_global_load_lds(                                          \
      (const __attribute__((address_space(1))) void*)(gp),                   \
      (__attribute__((address_space(3))) void*)(lp), 16, 0, 0)

__device__ __forceinline__ unsigned short f2bf(float f) {
  union { float f; unsigned int u; } v; v.f = f;
  unsigned int r = v.u + 0x7fffu + ((v.u >> 16) & 1u);
  return (unsigned short)(r >> 16);
}
__device__ __forceinline__ float bf2f(unsigned short s) {
  union { unsigned int u; float f; } v; v.u = ((unsigned int)s) << 16; return v.f;
}

__global__ void zero_i32(int* p, int n) {
  int i = blockIdx.x * blockDim.x + threadIdx.x;
  if (i < n) p[i] = 0;
}
__global__ void zero_f32(float* p, int n) {
  int i = blockIdx.x * blockDim.x + threadIdx.x;
  if (i < n) p[i] = 0.f;
}

// w (DxD f32, row-major [k][j]) -> wt (bf16, transposed [j][k])
__global__ void wconv_kernel(const float* __restrict__ w, unsigned short* __restrict__ wt) {
  int idx = blockIdx.x * blockDim.x + threadIdx.x; // 262144
  int k = idx >> 9, j = idx & 511;
  wt[j * 512 + k] = f2bf(w[idx]);
}

// ---- CSR build ----
__global__ void hist_kernel(const int* __restrict__ ei, int* __restrict__ deg, int E) {
  int e = blockIdx.x * blockDim.x + threadIdx.x;
  if (e < E) atomicAdd(&deg[ei[E + e]], 1);
}

__global__ void scan_blk(const int* __restrict__ in, int* __restrict__ loc,
                         int* __restrict__ bsum, int N) {
  __shared__ int tmp[256];
  int tid = threadIdx.x;
  int i = blockIdx.x * 256 + tid;
  int v = (i < N) ? in[i] : 0;
  int acc = v;
  tmp[tid] = v;
  __syncthreads();
  for (int s = 1; s < 256; s <<= 1) {
    int t = (tid >= s) ? tmp[tid - s] : 0;
    __syncthreads();
    acc += t;
    tmp[tid] = acc;
    __syncthreads();
  }
  if (i < N) loc[i] = acc - v;
  if (tid == 255) bsum[blockIdx.x] = acc;
}

__global__ void scan_add(const int* __restrict__ loc, const int* __restrict__ bpre,
                         int* __restrict__ off, int* __restrict__ cur, int N, int E) {
  int i = blockIdx.x * 256 + threadIdx.x;
  if (i < N) {
    int o = loc[i] + bpre[blockIdx.x];
    off[i] = o;
    cur[i] = o;
  }
  if (i == 0) off[N] = E;
}

__global__ void fill_kernel(const int* __restrict__ ei, int* __restrict__ cur,
                            int* __restrict__ srcl, int E) {
  int e = blockIdx.x * blockDim.x + threadIdx.x;
  if (e < E) {
    int d = ei[E + e];
    int p = atomicAdd(&cur[d], 1);
    srcl[p] = ei[e];
  }
}

// ---- gather: h[i] = bf16( y(i) + sum_{j in N(i)} y(j) )
// BN=false: input f32 x, y = x.   BN=true: input bf16 u, y = relu(u*sc+sh).
template<bool BN>
__global__ __launch_bounds__(256) void gather_kernel(
    const void* __restrict__ xin, const int* __restrict__ off,
    const int* __restrict__ srcl, const float* __restrict__ scale,
    const float* __restrict__ shift, unsigned short* __restrict__ hout, int N)
{
  int node = blockIdx.x * 4 + (threadIdx.x >> 6);
  if (node >= N) return;
  int c = (threadIdx.x & 63) * 8;

  f32x4 sc0, sc1, sh0, sh1;
  if (BN) {
    sc0 = *(const f32x4*)&scale[c];     sc1 = *(const f32x4*)&scale[c + 4];
    sh0 = *(const f32x4*)&shift[c];     sh1 = *(const f32x4*)&shift[c + 4];
  }

  f32x4 a0, a1;
  // load + transform one row into (v0,v1)
#define LOADROW(IDX, V0, V1)                                                  \
  do {                                                                        \
    if (BN) {                                                                 \
      const unsigned short* rp = (const unsigned short*)xin + (size_t)(IDX) * 512 + c; \
      short8 rv = *(const short8*)rp;                                         \
      for (int q = 0; q < 4; ++q) {                                           \
        V0[q] = bf2f((unsigned short)rv[q]);                                  \
        V1[q] = bf2f((unsigned short)rv[q + 4]);                              \
      }                                                                       \
      V0 = V0 * sc0 + sh0; V1 = V1 * sc1 + sh1;                               \
      for (int q = 0; q < 4; ++q) {                                           \
        V0[q] = fmaxf(V0[q], 0.f); V1[q] = fmaxf(V1[q], 0.f);                 \
      }                                                                       \
    } else {                                                                  \
      const float* rp = (const float*)xin + (size_t)(IDX) * 512 + c;          \
      V0 = *(const f32x4*)rp; V1 = *(const f32x4*)(rp + 4);                   \
    }                                                                         \
  } while (0)

  LOADROW(node, a0, a1);

  int b = off[node], e = off[node + 1];
  int p = b;
  while (p + 2 <= e) {
    int iA = srcl[p], iB = srcl[p + 1];
    f32x4 v0, v1, w0, w1;
    LOADROW(iA, v0, v1);
    LOADROW(iB, w0, w1);
    a0 += v0 + w0; a1 += v1 + w1;
    p += 2;
  }
  if (p < e) {
    int iA = srcl[p];
    f32x4 v0, v1;
    LOADROW(iA, v0, v1);
    a0 += v0; a1 += v1;
  }
#undef LOADROW

  short8 o;
  o[0] = f2bf(a0[0]); o[1] = f2bf(a0[1]); o[2] = f2bf(a0[2]); o[3] = f2bf(a0[3]);
  o[4] = f2bf(a1[0]); o[5] = f2bf(a1[1]); o[6] = f2bf(a1[2]); o[7] = f2bf(a1[3]);
  *(short8*)&hout[(size_t)node * 512 + c] = o;
}

// ---- GEMM: C[M x 512] = bf16( act(A[M x 512] @ W[512 x 512] + bias) ) ----
// 128x128 tile, 4 waves (2x2), BK=64, double-buffered LDS, global_load_lds
// with pre-swizzled global source + matching swizzled ds_read (conflict-free).
// 1D grid, i-major + bijective XCD-chunked swizzle. Epilogue: stats via
// shfl+atomics from f32 acc (pre-rounding), then LDS-staged coalesced C store.
template<bool RELU, bool STATS>
__global__ __launch_bounds__(256) void gemm_kernel(
    const unsigned short* __restrict__ A, const unsigned short* __restrict__ Wt,
    const float* __restrict__ bias, unsigned short* __restrict__ Cp, int M, int nwg,
    float* __restrict__ sum, float* __restrict__ sumsq)
{
  __shared__ unsigned short S[2][2][8192];  // 64 KB; epilogue reuses as [128][132]

  const int bid = blockIdx.x;
  const int xcd = bid & 7, pos = bid >> 3;
  const int q8 = nwg >> 3, r8 = nwg & 7;
  const int base = (xcd < r8) ? xcd * (q8 + 1) : r8 * (q8 + 1) + (xcd - r8) * q8;
  const int wg = base + pos;
  const int i0 = (wg >> 2) * 128;
  const int j0 = (wg & 3) * 128;

  const int tid = threadIdx.x;
  const int lane = tid & 63;
  const int wid = tid >> 6;
  const int wr = wid >> 1, wc = wid & 1;
  const int l15 = lane & 15, lg = lane >> 4;

  // staging: chunk c covers rows c*8..c*8+7; lane l -> row c*8+(l>>3), col16
  // pre-swizzled (l&7)^(l>>3)
  const int srow = lane >> 3;
  const int scol = (lane & 7) ^ srow;
  const unsigned short* gA = A + (size_t)(i0 + srow) * 512 + scol * 8;
  const unsigned short* gB = Wt + (size_t)(j0 + srow) * 512 + scol * 8;

  const int cpr = lg ^ (l15 & 7);
  const int aoff0 = (wr * 64 + l15) * 64 + cpr * 8;
  const int aoff1 = (wr * 64 + l15) * 64 + (cpr ^ 4) * 8;
  const int boff0 = (wc * 64 + l15) * 64 + cpr * 8;
  const int boff1 = (wc * 64 + l15) * 64 + (cpr ^ 4) * 8;

  f32x4 acc[4][4];
#pragma unroll
  for (int m = 0; m < 4; ++m)
#pragma unroll
    for (int n = 0; n < 4; ++n)
      acc[m][n] = (f32x4){0.f, 0.f, 0.f, 0.f};

#pragma unroll
  for (int j = 0; j < 4; ++j) {
    int c = wid * 4 + j;
    GLL16(gA + (size_t)c * 4096, &S[0][0][c * 512]);
    GLL16(gB + (size_t)c * 4096, &S[0][1][c * 512]);
  }
  __syncthreads();

#pragma unroll
  for (int kt = 0; kt < 8; ++kt) {
    const int cur = kt & 1;
    if (kt < 7) {
      const int nxt = cur ^ 1;
      const int kk = (kt + 1) * 64;
#pragma unroll
      for (int j = 0; j < 4; ++j) {
        int c = wid * 4 + j;
        GLL16(gA + (size_t)c * 4096 + kk, &S[nxt][0][c * 512]);
        GLL16(gB + (size_t)c * 4096 + kk, &S[nxt][1][c * 512]);
      }
    }

    short8 a[4][2], b[4][2];
#pragma unroll
    for (int m = 0; m < 4; ++m) {
      a[m][0] = *(const short8*)&S[cur][0][m * 1024 + aoff0];
      a[m][1] = *(const short8*)&S[cur][0][m * 1024 + aoff1];
    }
#pragma unroll
    for (int n = 0; n < 4; ++n) {
      b[n][0] = *(const short8*)&S[cur][1][n * 1024 + boff0];
      b[n][1] = *(const short8*)&S[cur][1][n * 1024 + boff1];
    }
#pragma unroll
    for (int ks = 0; ks < 2; ++ks)
#pragma unroll
      for (int m = 0; m < 4; ++m)
#pragma unroll
        for (int n = 0; n < 4; ++n)
          acc[m][n] = __builtin_amdgcn_mfma_f32_16x16x32_bf16(a[m][ks], b[n][ks],
                                                              acc[m][n], 0, 0, 0);
    __syncthreads();
  }

  // ---- epilogue: stats (f32, pre-round) + LDS-staged coalesced bf16 store
  unsigned short* T = (unsigned short*)S;  // [128][132] shorts, 264B row stride

#pragma unroll
  for (int n = 0; n < 4; ++n) {
    const int coll = wc * 64 + n * 16 + l15;
    const float bv = bias[j0 + coll];
    float sv = 0.f, qv = 0.f;
#pragma unroll
    for (int m = 0; m < 4; ++m) {
      const int rowl0 = wr * 64 + m * 16 + lg * 4;
#pragma unroll
      for (int q = 0; q < 4; ++q) {
        float v = acc[m][n][q] + bv;
        if (RELU) v = fmaxf(v, 0.f);
        if (STATS && (i0 + rowl0 + q) < M) { sv += v; qv += v * v; }
        T[(rowl0 + q) * 132 + coll] = f2bf(v);
      }
    }
    if (STATS) {
      sv += __shfl_xor(sv, 16); qv += __shfl_xor(qv, 16);
      sv += __shfl_xor(sv, 32); qv += __shfl_xor(qv, 32);
      if (lg == 0) {
        atomicAdd(&sum[j0 + coll], sv);
        atomicAdd(&sumsq[j0 + coll], qv);
      }
    }
  }
  __syncthreads();

  {
    const int ch = tid & 15;      // 8-col chunk; lanes 0..15 span one 256B row
    const int rbase = tid >> 4;   // 0..15
#pragma unroll
    for (int i = 0; i < 8; ++i) {
      int rl = rbase + i * 16;
      int gr = i0 + rl;
      if (gr < M) {
        short8 vv = *(const short8*)&T[rl * 132 + ch * 8];
        *(short8*)&Cp[(size_t)gr * 512 + j0 + ch * 8] = vv;
      }
    }
  }
}

__global__ void finalize_kernel(const float* __restrict__ sum, const float* __restrict__ sumsq,
                                const float* __restrict__ gamma, const float* __restrict__ beta,
                                float* __restrict__ scale, float* __restrict__ shift, int M) {
  int c = blockIdx.x * blockDim.x + threadIdx.x;
  if (c < 512) {
    float inv = 1.f / (float)M;
    float mu = sum[c] * inv;
    float var = sumsq[c] * inv - mu * mu;
    float sc = gamma[c] * rsqrtf(var + BN_EPS);
    scale[c] = sc;
    shift[c] = beta[c] - mu * sc;
  }
}

// d_out = relu(u*scale+shift) + x   (u bf16, x/out f32); thread handles 8 cols
__global__ void bn_res_kernel(const unsigned short* __restrict__ u,
                              const float* __restrict__ scale,
                              const float* __restrict__ shift,
                              const float* __restrict__ x,
                              float* __restrict__ y, int n8) {
  int gid = blockIdx.x * blockDim.x + threadIdx.x;
  if (gid >= n8) return;
  size_t e0 = (size_t)gid * 8;
  int c0 = (int)(e0 & 511);
  short8 uu = *(const short8*)&u[e0];
  f32x4 sc0 = *(const f32x4*)&scale[c0], sc1 = *(const f32x4*)&scale[c0 + 4];
  f32x4 sh0 = *(const f32x4*)&shift[c0], sh1 = *(const f32x4*)&shift[c0 + 4];
  f32x4 x0 = *(const f32x4*)&x[e0],      x1 = *(const f32x4*)&x[e0 + 4];
  f32x4 r0, r1;
#pragma unroll
  for (int q = 0; q < 4; ++q) {
    r0[q] = fmaxf(bf2f((unsigned short)uu[q]) * sc0[q] + sh0[q], 0.f) + x0[q];
    r1[q] = fmaxf(bf2f((unsigned short)uu[q + 4]) * sc1[q] + sh1[q], 0.f) + x1[q];
  }
  *(f32x4*)&y[e0] = r0;
  *(f32x4*)&y[e0 + 4] = r1;
}

extern "C" void kernel_launch(void* const* d_in, const int* in_sizes, int n_in,
                              void* d_out, int out_size, void* d_ws, size_t ws_size,
                              hipStream_t stream) {
  const float* x   = (const float*)d_in[0];
  const int*   ei  = (const int*)d_in[1];
  const float* w1a = (const float*)d_in[2];
  const float* b1a = (const float*)d_in[3];
  const float* w1b = (const float*)d_in[4];
  const float* b1b = (const float*)d_in[5];
  const float* g1  = (const float*)d_in[6];
  const float* be1 = (const float*)d_in[7];
  const float* w2a = (const float*)d_in[8];
  const float* b2a = (const float*)d_in[9];
  const float* w2b = (const float*)d_in[10];
  const float* b2b = (const float*)d_in[11];
  const float* g2  = (const float*)d_in[12];
  const float* be2 = (const float*)d_in[13];

  const int N = in_sizes[0] / 512;
  const int E = in_sizes[1] / 2;
  const size_t ND = (size_t)N * 512;

  char* ws = (char*)d_ws;
  unsigned short* hbf = (unsigned short*)ws;              // ND bf16
  unsigned short* t1  = (unsigned short*)(ws + ND * 2);   // ND bf16
  unsigned short* u   = (unsigned short*)(ws + ND * 4);   // ND bf16
  unsigned short* wt  = (unsigned short*)(ws + ND * 6);   // 4 x 512x512 bf16
  char* p = ws + ND * 6 + (size_t)4 * 262144 * 2;
  float* st = (float*)p;                                  // 4096 f32
  float* sum1 = st,        *sq1 = st + 512;
  float* sum2 = st + 1024, *sq2 = st + 1536;
  float* scale1 = st + 2048, *shift1 = st + 2560;
  float* scale2 = st + 3072, *shift2 = st + 3584;
  p += 4096 * 4;
  int* deg  = (int*)p;             p += (size_t)(N + 1) * 4;
  int* off  = (int*)p;             p += (size_t)(N + 1) * 4;
  int* cur  = (int*)p;             p += (size_t)N * 4;
  int* loc  = (int*)p;             p += (size_t)N * 4;
  int* bsum = (int*)p;             p += 256 * 4;
  int* bpre = (int*)p;             p += 256 * 4;
  int* tot  = (int*)p;             p += 4;
  int* srcl = (int*)p;             p += (size_t)E * 4;

  const int n8 = (int)(ND / 8);
  const int nbN = (N + 255) / 256;
  const int nbE = (E + 255) / 256;
  const int nwg = ((N + 127) / 128) * 4;
  const int ggather = (N + 3) / 4;

  // weight prep + zeroing
  wconv_kernel<<<1024, 256, 0, stream>>>(w1a, wt);
  wconv_kernel<<<1024, 256, 0, stream>>>(w1b, wt + 262144);
  wconv_kernel<<<1024, 256, 0, stream>>>(w2a, wt + 2 * 262144);
  wconv_kernel<<<1024, 256, 0, stream>>>(w2b, wt + 3 * 262144);
  zero_f32<<<8, 256, 0, stream>>>(st, 2048);
  zero_i32<<<nbN, 256, 0, stream>>>(deg, N);

  // CSR build
  hist_kernel<<<nbE, 256, 0, stream>>>(ei, deg, E);
  scan_blk<<<nbN, 256, 0, stream>>>(deg, loc, bsum, N);
  scan_blk<<<1, 256, 0, stream>>>(bsum, bpre, tot, nbN);
  scan_add<<<nbN, 256, 0, stream>>>(loc, bpre, off, cur, N, E);
  fill_kernel<<<nbE, 256, 0, stream>>>(ei, cur, srcl, E);

  // ---- layer 1 ----
  gather_kernel<false><<<ggather, 256, 0, stream>>>(x, off, srcl, nullptr, nullptr, hbf, N);
  gemm_kernel<true, false><<<nwg, 256, 0, stream>>>(hbf, wt, b1a, t1, N, nwg,
                                                    nullptr, nullptr);
  gemm_kernel<false, true><<<nwg, 256, 0, stream>>>(t1, wt + 262144, b1b, u, N, nwg,
                                                    sum1, sq1);
  finalize_kernel<<<2, 256, 0, stream>>>(sum1, sq1, g1, be1, scale1, shift1, N);

  // ---- layer 2 (BN applied on the fly inside gather, u is bf16) ----
  gather_kernel<true><<<ggather, 256, 0, stream>>>(u, off, srcl, scale1, shift1, hbf, N);
  gemm_kernel<true, false><<<nwg, 256, 0, stream>>>(hbf, wt + 2 * 262144, b2a, t1, N,
                                                    nwg, nullptr, nullptr);
  gemm_kernel<false, true><<<nwg, 256, 0, stream>>>(t1, wt + 3 * 262144, b2b, u, N,
                                                    nwg, sum2, sq2);
  finalize_kernel<<<2, 256, 0, stream>>>(sum2, sq2, g2, be2, scale2, shift2, N);
  bn_res_kernel<<<(n8 + 255) / 256, 256, 0, stream>>>(u, scale2, shift2,
                                                      x, (float*)d_out, n8);
}